// Round 20
// baseline (418.536 us; speedup 1.0000x reference)
//
#include <hip/hip_runtime.h>
#include <hip/hip_fp16.h>

#define N_NODES 50000
#define E_EDGES 800000
#define F_IN 512
#define HID 128
#define N_LAYERS 4
#define C_OUT 40
#define SCAN_BLOCKS 196   // ceil(50000/256)

typedef __attribute__((ext_vector_type(8))) short bf16x8;
typedef __attribute__((ext_vector_type(4))) float f32x4;

#define MFMA16(a, b, c) __builtin_amdgcn_mfma_f32_16x16x32_bf16(a, b, c, 0, 0, 0)

// split fp32 into bf16 hi (RNE) + bf16 lo (residual); a ~= hi + lo with ~2^-17 rel error
__device__ __forceinline__ void split2(float a, unsigned short& hi, unsigned short& lo) {
    unsigned u = __float_as_uint(a);
    unsigned r = u + 0x7FFFu + ((u >> 16) & 1u);
    hi = (unsigned short)(r >> 16);
    float hf = __uint_as_float(((unsigned)hi) << 16);
    lo = (unsigned short)(__float_as_uint(a - hf) >> 16);
}

// 8 floats (two float4, k-contiguous) -> bf16x8 hi/lo fragments
__device__ __forceinline__ void splitfrag(float4 a, float4 b, bf16x8& h8, bf16x8& l8) {
    unsigned short hh, ll;
    float v[8] = {a.x, a.y, a.z, a.w, b.x, b.y, b.z, b.w};
    #pragma unroll
    for (int i = 0; i < 8; i++) {
        split2(v[i], hh, ll);
        h8[i] = (short)hh;
        l8[i] = (short)ll;
    }
}

// async global->LDS 16B DMA
__device__ __forceinline__ void async16(void* lds, const void* g) {
    __builtin_amdgcn_global_load_lds(
        (const __attribute__((address_space(1))) unsigned*)g,
        (__attribute__((address_space(3))) unsigned*)lds, 16, 0, 0);
}

// ---------------- degree ----------------
__global__ void indeg_count(const int* __restrict__ ei, int* __restrict__ indeg) {
    int e = blockIdx.x * 256 + threadIdx.x;
    if (e < E_EDGES) {
        unsigned d = (unsigned)ei[E_EDGES + e];
        if (d < N_NODES) atomicAdd(&indeg[d], 1);
    }
}

// ---------------- 3-phase parallel exclusive scan (+ dinv fused in p1) ----------------
__global__ void scan_p1(const int* __restrict__ indeg, int* __restrict__ bsum,
                        float* __restrict__ dinv) {
    __shared__ int red[4];
    int i = blockIdx.x * 256 + threadIdx.x;
    int v = (i < N_NODES) ? indeg[i] : 0;
    if (i < N_NODES) dinv[i] = rsqrtf(1.0f + (float)v);   // +1 self-loop
    int s = v;
    #pragma unroll
    for (int off = 32; off > 0; off >>= 1) s += __shfl_down(s, off, 64);
    if ((threadIdx.x & 63) == 0) red[threadIdx.x >> 6] = s;
    __syncthreads();
    if (threadIdx.x == 0) bsum[blockIdx.x] = red[0] + red[1] + red[2] + red[3];
}

__launch_bounds__(256)
__global__ void scan_p2(const int* __restrict__ bsum, int* __restrict__ boff,
                        int* __restrict__ rowptr) {
    __shared__ int s[256];
    int t = threadIdx.x;
    int v = (t < SCAN_BLOCKS) ? bsum[t] : 0;
    s[t] = v;
    __syncthreads();
    #pragma unroll
    for (int off = 1; off < 256; off <<= 1) {
        int a = s[t];
        int b = (t >= off) ? s[t - off] : 0;
        __syncthreads();
        s[t] = a + b;
        __syncthreads();
    }
    if (t < SCAN_BLOCKS) boff[t] = (t == 0) ? 0 : s[t - 1];
    if (t == 255) rowptr[N_NODES] = s[SCAN_BLOCKS - 1];
}

__launch_bounds__(256)
__global__ void scan_p3(const int* __restrict__ indeg, const int* __restrict__ boff,
                        int* __restrict__ rowptr, int* __restrict__ cursor) {
    __shared__ int s[256];
    int t = threadIdx.x;
    int i = blockIdx.x * 256 + t;
    int v = (i < N_NODES) ? indeg[i] : 0;
    s[t] = v;
    __syncthreads();
    #pragma unroll
    for (int off = 1; off < 256; off <<= 1) {
        int a = s[t];
        int b = (t >= off) ? s[t - off] : 0;
        __syncthreads();
        s[t] = a + b;
        __syncthreads();
    }
    if (i < N_NODES) {
        int excl = boff[blockIdx.x] + s[t] - v;
        rowptr[i] = excl;
        cursor[i] = excl;
    }
}

// ---------------- CSR fill ----------------
__global__ void csr_fill(const int* __restrict__ ei, int* __restrict__ cursor,
                         int* __restrict__ csr) {
    int e = blockIdx.x * 256 + threadIdx.x;
    if (e < E_EDGES) {
        unsigned s = (unsigned)ei[e];
        unsigned d = (unsigned)ei[E_EDGES + e];
        if (s < N_NODES && d < N_NODES) {
            int pos = atomicAdd(&cursor[d], 1);
            csr[pos] = (int)s;
        }
    }
}

// ---------------- merged weight prep: fp32 W[K][N] -> hi/lo bf16 [N][K] (+ W_out padded) ----------------
__global__ void wprep(const float* __restrict__ Wi, const float* __restrict__ Wl,
                      const float* __restrict__ Wo,
                      unsigned short* __restrict__ Wth, unsigned short* __restrict__ Wtl,
                      unsigned short* __restrict__ Wlth, unsigned short* __restrict__ Wltl,
                      unsigned short* __restrict__ Woth, unsigned short* __restrict__ Wotl) {
    int idx = blockIdx.x * 256 + threadIdx.x;
    unsigned short hi, lo;
    if (idx < F_IN * HID) {
        int k = idx >> 7, n = idx & 127;
        split2(Wi[idx], hi, lo);
        Wth[(size_t)n * F_IN + k] = hi;
        Wtl[(size_t)n * F_IN + k] = lo;
    } else if (idx < 2 * F_IN * HID) {
        int j = idx - F_IN * HID;
        int l = j >> 14, rem = j & 16383;
        int k = rem >> 7, n = rem & 127;
        split2(Wl[j], hi, lo);
        Wlth[(size_t)l * HID * HID + n * HID + k] = hi;
        Wltl[(size_t)l * HID * HID + n * HID + k] = lo;
    } else if (idx < 2 * F_IN * HID + 48 * HID) {
        int j = idx - 2 * F_IN * HID;          // 0..6143
        int n = j >> 7, k = j & 127;           // n: padded col 0..47
        float w = (n < C_OUT) ? Wo[(size_t)k * C_OUT + n] : 0.f;
        split2(w, hi, lo);
        Woth[(size_t)n * HID + k] = hi;
        Wotl[(size_t)n * HID + k] = lo;
    }
}

// ---------------- input GEMM (MFMA split-bf16) ----------------
// v2: A staged as RAW fp32 via global_load_lds with pre-swizzled source (m151 pattern);
// split2 at fragment-read time (overlaps MFMA across waves). LDS 24 KB -> 6 blocks/CU.
// Epilogue: x0 = relu(x@W+b); res0 = (0.8dd^2+0.2)*x0; g16 = fp16(dd*x0).
__launch_bounds__(256)
__global__ void gemm_in_mfma(const float* __restrict__ x,
                             const unsigned short* __restrict__ Bth,
                             const unsigned short* __restrict__ Btl,
                             const float* __restrict__ bi,
                             const float* __restrict__ dinv,
                             float* __restrict__ x0out,
                             float* __restrict__ res0,
                             __half* __restrict__ g16) {
    __shared__ __align__(16) float Af[64 * 32];              // 8 KB fp32
    __shared__ __align__(16) unsigned short Bh[128 * 32];    // 8 KB
    __shared__ __align__(16) unsigned short Bl[128 * 32];    // 8 KB
    const int t = threadIdx.x;
    const int lane = t & 63;
    const int wv = t >> 6;
    const int wr = wv >> 1, wc = wv & 1;
    const int row0 = blockIdx.x * 64;
    const int fr = lane & 15;
    const int fkg = lane >> 4;          // 16B granule group 0..3

    f32x4 acc[2][4] = {};

    for (int step = 0; step < 16; step++) {
        const int k0 = step * 32;
        // B DMA (r13-proven swizzle, 0 conflicts)
        #pragma unroll
        for (int i = 0; i < 2; i++) {
            int g = t + i * 256;                 // 0..511
            int n = g >> 2, kg = g & 3;
            int kgp = kg ^ ((n >> 1) & 3);
            size_t src = (size_t)n * F_IN + k0 + kgp * 8;
            async16(&Bh[g * 8], &Bth[src]);
            async16(&Bl[g * 8], &Btl[src]);
        }
        // A DMA: fp32 [64][32], granule (r,g) holds source granule g^(r&7)
        #pragma unroll
        for (int i = 0; i < 2; i++) {
            int gi = t + i * 256;                // granule 0..511
            int r = gi >> 3, g = gi & 7;
            int grow = row0 + r;
            if (grow < N_NODES) {
                int gp = g ^ (r & 7);
                async16(&Af[gi * 4], &x[(size_t)grow * F_IN + k0 + gp * 4]);
            }
        }
        __syncthreads();   // drains all DMA

        bf16x8 ah[2], al[2];
        #pragma unroll
        for (int mt = 0; mt < 2; mt++) {
            int arow = wr * 32 + mt * 16 + fr;
            int sw = arow & 7;
            float4 fa = *(float4*)&Af[(arow * 8 + ((2 * fkg) ^ sw)) * 4];
            float4 fb = *(float4*)&Af[(arow * 8 + ((2 * fkg + 1) ^ sw)) * 4];
            splitfrag(fa, fb, ah[mt], al[mt]);
        }
        #pragma unroll
        for (int nt = 0; nt < 4; nt++) {
            int n = wc * 64 + nt * 16 + fr;
            int bidx = n * 32 + (fkg ^ ((n >> 1) & 3)) * 8;
            bf16x8 bh = *(bf16x8*)&Bh[bidx];
            bf16x8 bl = *(bf16x8*)&Bl[bidx];
            #pragma unroll
            for (int mt = 0; mt < 2; mt++) {
                acc[mt][nt] = MFMA16(al[mt], bh, acc[mt][nt]);
                acc[mt][nt] = MFMA16(ah[mt], bl, acc[mt][nt]);
                acc[mt][nt] = MFMA16(ah[mt], bh, acc[mt][nt]);
            }
        }
        __syncthreads();
    }

    const int dcol = lane & 15;
    const int dr0 = (lane >> 4) * 4;
    float dv[2][4];
    #pragma unroll
    for (int mt = 0; mt < 2; mt++)
        #pragma unroll
        for (int j = 0; j < 4; j++) {
            int grow = row0 + wr * 32 + mt * 16 + dr0 + j;
            dv[mt][j] = (grow < N_NODES) ? dinv[grow] : 0.f;
        }
    #pragma unroll
    for (int nt = 0; nt < 4; nt++) {
        int gcol = wc * 64 + nt * 16 + dcol;
        float b = bi[gcol];
        #pragma unroll
        for (int mt = 0; mt < 2; mt++) {
            #pragma unroll
            for (int j = 0; j < 4; j++) {
                int grow = row0 + wr * 32 + mt * 16 + dr0 + j;
                if (grow < N_NODES) {
                    float d = dv[mt][j];
                    float v = fmaxf(acc[mt][nt][j] + b, 0.f);
                    size_t off = (size_t)grow * HID + gcol;
                    x0out[off] = v;
                    res0[off] = (0.8f * d * d + 0.2f) * v;   // c2*h + 0.1*x0 with h==x0
                    g16[off] = __float2half(d * v);
                }
            }
        }
    }
}

// ---------------- aggregate: full wave per node; comb = 0.8*dd*sum(g16[src]) + res ----------------
__launch_bounds__(256)
__global__ void aggregate(const int* __restrict__ rowptr, const int* __restrict__ csr,
                          const float* __restrict__ dinv,
                          const __half* __restrict__ g16,
                          const float* __restrict__ res,
                          float* __restrict__ comb) {
    const int node = blockIdx.x * 4 + (threadIdx.x >> 6);
    const int lane = threadIdx.x & 63;
    if (node >= N_NODES) return;

    const unsigned* g32 = (const unsigned*)g16;   // lane owns dword = feats 2*lane, 2*lane+1
    const float dd = dinv[node];
    const int beg = rowptr[node];                 // wave-uniform -> scalar loads
    const int end = rowptr[node + 1];

    float a0 = 0.f, a1 = 0.f, b0 = 0.f, b1 = 0.f;

    #define GACC(r, i) { \
        __half2 p = *(__half2*)&(r); \
        float2 f = __half22float2(p); \
        if ((i) & 1) { b0 += f.x; b1 += f.y; } else { a0 += f.x; a1 += f.y; } }

    int e = beg;
    for (; e + 16 <= end; e += 16) {
        unsigned r[16];
        #pragma unroll
        for (int i = 0; i < 16; i++) r[i] = g32[(size_t)csr[e + i] * 64 + lane];
        #pragma unroll
        for (int i = 0; i < 16; i++) GACC(r[i], i)
    }
    for (; e + 4 <= end; e += 4) {
        unsigned r[4];
        #pragma unroll
        for (int i = 0; i < 4; i++) r[i] = g32[(size_t)csr[e + i] * 64 + lane];
        #pragma unroll
        for (int i = 0; i < 4; i++) GACC(r[i], i)
    }
    for (; e < end; e++) {
        unsigned r = g32[(size_t)csr[e] * 64 + lane];
        GACC(r, 0)
    }
    #undef GACC

    float s0 = a0 + b0, s1 = a1 + b1;
    const float c1 = 0.8f * dd;
    float2 rv = ((const float2*)res)[(size_t)node * 64 + lane];
    float2 o;
    o.x = fmaf(c1, s0, rv.x);
    o.y = fmaf(c1, s1, rv.y);
    ((float2*)comb)[(size_t)node * 64 + lane] = o;
}

// ---------------- layer GEMM: h = SReLU(comb @ W); res = c2*h + 0.1*x0; g16 = fp16(dd*h) ----------------
// BK=32 single-buffered B chunk -> LDS 48 KB -> 3 blocks/CU. (r14-verified structure)
__launch_bounds__(256)
__global__ void gemm_layer_mfma(const unsigned short* __restrict__ Bth,
                                const unsigned short* __restrict__ Btl,
                                const float* __restrict__ sb,
                                const float* __restrict__ dinv,
                                const float* __restrict__ comb,
                                const float* __restrict__ x0,
                                float* __restrict__ res,
                                __half* __restrict__ g16) {
    __shared__ __align__(16) unsigned short Ah[64 * 128];   // 16 KB
    __shared__ __align__(16) unsigned short Al[64 * 128];   // 16 KB
    __shared__ __align__(16) unsigned short Bh[128 * 32];   // 8 KB
    __shared__ __align__(16) unsigned short Bl[128 * 32];   // 8 KB
    const int t = threadIdx.x;
    const int lane = t & 63;
    const int wv = t >> 6;
    const int wr = wv >> 1, wc = wv & 1;
    const int row0 = blockIdx.x * 64;
    const int fr = lane & 15;
    const int fkg = lane >> 4;

    f32x4 acc[2][4] = {};

    auto stageB = [&](int k0) {
        #pragma unroll
        for (int i = 0; i < 2; i++) {
            int g = t + i * 256;
            int n = g >> 2, kg = g & 3;
            int kgp = kg ^ ((n >> 1) & 3);
            size_t src = (size_t)n * HID + k0 + kgp * 8;
            async16(&Bh[g * 8], &Bth[src]);
            async16(&Bl[g * 8], &Btl[src]);
        }
    };

    stageB(0);
    #pragma unroll
    for (int i = 0; i < 8; i++) {
        int q = t + i * 256;
        int r = q >> 5, c4 = q & 31;
        int grow = row0 + r;
        float4 v = make_float4(0.f, 0.f, 0.f, 0.f);
        if (grow < N_NODES) v = *(const float4*)&comb[(size_t)grow * HID + c4 * 4];
        ushort4 uh, ul;
        split2(v.x, uh.x, ul.x); split2(v.y, uh.y, ul.y);
        split2(v.z, uh.z, ul.z); split2(v.w, uh.w, ul.w);
        int idx = (r * 128 + c4 * 4) ^ ((r & 7) << 3);
        *(ushort4*)&Ah[idx] = uh;
        *(ushort4*)&Al[idx] = ul;
    }
    __syncthreads();

    #pragma unroll
    for (int step = 0; step < 4; step++) {
        bf16x8 ah[2], al[2];
        #pragma unroll
        for (int mt = 0; mt < 2; mt++) {
            int arow = wr * 32 + mt * 16 + fr;
            int aidx = (arow * 128 + step * 32 + fkg * 8) ^ ((arow & 7) << 3);
            ah[mt] = *(bf16x8*)&Ah[aidx];
            al[mt] = *(bf16x8*)&Al[aidx];
        }
        #pragma unroll
        for (int nt = 0; nt < 4; nt++) {
            int n = wc * 64 + nt * 16 + fr;
            int bidx = n * 32 + (fkg ^ ((n >> 1) & 3)) * 8;
            bf16x8 bh = *(bf16x8*)&Bh[bidx];
            bf16x8 bl = *(bf16x8*)&Bl[bidx];
            #pragma unroll
            for (int mt = 0; mt < 2; mt++) {
                acc[mt][nt] = MFMA16(al[mt], bh, acc[mt][nt]);
                acc[mt][nt] = MFMA16(ah[mt], bl, acc[mt][nt]);
                acc[mt][nt] = MFMA16(ah[mt], bh, acc[mt][nt]);
            }
        }
        __syncthreads();
        if (step < 3) {
            stageB((step + 1) * 32);
            __syncthreads();
        }
    }

    const int dcol = lane & 15;
    const int dr0 = (lane >> 4) * 4;
    float dv[2][4];
    #pragma unroll
    for (int mt = 0; mt < 2; mt++)
        #pragma unroll
        for (int j = 0; j < 4; j++) {
            int grow = row0 + wr * 32 + mt * 16 + dr0 + j;
            dv[mt][j] = (grow < N_NODES) ? dinv[grow] : 0.f;
        }
    #pragma unroll
    for (int nt = 0; nt < 4; nt++) {
        int gcol = wc * 64 + nt * 16 + dcol;
        float s = sb[gcol];
        #pragma unroll
        for (int mt = 0; mt < 2; mt++) {
            #pragma unroll
            for (int j = 0; j < 4; j++) {
                int grow = row0 + wr * 32 + mt * 16 + dr0 + j;
                if (grow < N_NODES) {
                    float d = dv[mt][j];
                    float v = fmaxf(acc[mt][nt][j], s);
                    size_t off = (size_t)grow * HID + gcol;
                    res[off] = fmaf(0.8f * d * d + 0.1f, v, 0.1f * x0[off]);
                    g16[off] = __float2half(d * v);
                }
            }
        }
    }
}

// ---------------- last layer GEMM + fused output GEMM (r15-verified win) ----------------
__launch_bounds__(256)
__global__ void gemm_layer_out(const unsigned short* __restrict__ Bth,
                               const unsigned short* __restrict__ Btl,
                               const float* __restrict__ sb,
                               const unsigned short* __restrict__ Woth,
                               const unsigned short* __restrict__ Wotl,
                               const float* __restrict__ bo,
                               const float* __restrict__ comb,
                               float* __restrict__ out) {
    __shared__ __align__(16) unsigned short Ah[64 * 128];
    __shared__ __align__(16) unsigned short Al[64 * 128];
    __shared__ __align__(16) unsigned short Bh[128 * 32];
    __shared__ __align__(16) unsigned short Bl[128 * 32];
    const int t = threadIdx.x;
    const int lane = t & 63;
    const int wv = t >> 6;
    const int wr = wv >> 1, wc = wv & 1;
    const int row0 = blockIdx.x * 64;
    const int fr = lane & 15;
    const int fkg = lane >> 4;

    f32x4 acc[2][4] = {};

    auto stageB = [&](int k0) {
        #pragma unroll
        for (int i = 0; i < 2; i++) {
            int g = t + i * 256;
            int n = g >> 2, kg = g & 3;
            int kgp = kg ^ ((n >> 1) & 3);
            size_t src = (size_t)n * HID + k0 + kgp * 8;
            async16(&Bh[g * 8], &Bth[src]);
            async16(&Bl[g * 8], &Btl[src]);
        }
    };

    stageB(0);
    #pragma unroll
    for (int i = 0; i < 8; i++) {
        int q = t + i * 256;
        int r = q >> 5, c4 = q & 31;
        int grow = row0 + r;
        float4 v = make_float4(0.f, 0.f, 0.f, 0.f);
        if (grow < N_NODES) v = *(const float4*)&comb[(size_t)grow * HID + c4 * 4];
        ushort4 uh, ul;
        split2(v.x, uh.x, ul.x); split2(v.y, uh.y, ul.y);
        split2(v.z, uh.z, ul.z); split2(v.w, uh.w, ul.w);
        int idx = (r * 128 + c4 * 4) ^ ((r & 7) << 3);
        *(ushort4*)&Ah[idx] = uh;
        *(ushort4*)&Al[idx] = ul;
    }
    __syncthreads();

    #pragma unroll
    for (int step = 0; step < 4; step++) {
        bf16x8 ah[2], al[2];
        #pragma unroll
        for (int mt = 0; mt < 2; mt++) {
            int arow = wr * 32 + mt * 16 + fr;
            int aidx = (arow * 128 + step * 32 + fkg * 8) ^ ((arow & 7) << 3);
            ah[mt] = *(bf16x8*)&Ah[aidx];
            al[mt] = *(bf16x8*)&Al[aidx];
        }
        #pragma unroll
        for (int nt = 0; nt < 4; nt++) {
            int n = wc * 64 + nt * 16 + fr;
            int bidx = n * 32 + (fkg ^ ((n >> 1) & 3)) * 8;
            bf16x8 bh = *(bf16x8*)&Bh[bidx];
            bf16x8 bl = *(bf16x8*)&Bl[bidx];
            #pragma unroll
            for (int mt = 0; mt < 2; mt++) {
                acc[mt][nt] = MFMA16(al[mt], bh, acc[mt][nt]);
                acc[mt][nt] = MFMA16(ah[mt], bl, acc[mt][nt]);
                acc[mt][nt] = MFMA16(ah[mt], bh, acc[mt][nt]);
            }
        }
        __syncthreads();
        if (step < 3) {
            stageB((step + 1) * 32);
            __syncthreads();
        }
    }

    // SReLU -> h4 back into A-LDS (split bf16, same swizzle; A is free now)
    const int dcol = lane & 15;
    const int dr0 = (lane >> 4) * 4;
    #pragma unroll
    for (int nt = 0; nt < 4; nt++) {
        int col = wc * 64 + nt * 16 + dcol;
        float s = sb[col];
        #pragma unroll
        for (int mt = 0; mt < 2; mt++) {
            #pragma unroll
            for (int j = 0; j < 4; j++) {
                int row = wr * 32 + mt * 16 + dr0 + j;
                float v = fmaxf(acc[mt][nt][j], s);
                unsigned short hi, lo;
                split2(v, hi, lo);
                int idx = (row * 128 + col) ^ ((row & 7) << 3);
                Ah[idx] = hi;
                Al[idx] = lo;
            }
        }
    }
    __syncthreads();

    // out phase: wave wv owns rows wv*16..+15; 3 n-tiles (48 padded cols), K=128
    f32x4 oacc[3] = {};
    #pragma unroll
    for (int kk = 0; kk < 4; kk++) {
        int arow = wv * 16 + fr;
        int aidx = (arow * 128 + kk * 32 + fkg * 8) ^ ((arow & 7) << 3);
        bf16x8 ah = *(bf16x8*)&Ah[aidx];
        bf16x8 al = *(bf16x8*)&Al[aidx];
        #pragma unroll
        for (int nt = 0; nt < 3; nt++) {
            size_t boff = (size_t)(nt * 16 + fr) * HID + kk * 32 + fkg * 8;
            bf16x8 bh = *(const bf16x8*)&Woth[boff];
            bf16x8 bl = *(const bf16x8*)&Wotl[boff];
            oacc[nt] = MFMA16(al, bh, oacc[nt]);
            oacc[nt] = MFMA16(ah, bl, oacc[nt]);
            oacc[nt] = MFMA16(ah, bh, oacc[nt]);
        }
    }
    #pragma unroll
    for (int nt = 0; nt < 3; nt++) {
        int gcol = nt * 16 + dcol;
        if (gcol < C_OUT) {
            float b = bo[gcol];
            #pragma unroll
            for (int j = 0; j < 4; j++) {
                int grow = row0 + wv * 16 + dr0 + j;
                if (grow < N_NODES)
                    out[(size_t)grow * C_OUT + gcol] = oacc[nt][j] + b;
            }
        }
    }
}

// ---------------- launch ----------------
extern "C" void kernel_launch(void* const* d_in, const int* in_sizes, int n_in,
                              void* d_out, int out_size, void* d_ws, size_t ws_size,
                              hipStream_t stream) {
    const float* x   = (const float*)d_in[0];
    const int*   ei  = (const int*)d_in[1];
    const float* Wi  = (const float*)d_in[2];
    const float* bi  = (const float*)d_in[3];
    const float* Wls = (const float*)d_in[4];
    const float* sbs = (const float*)d_in[5];
    const float* Wo  = (const float*)d_in[6];
    const float* bo  = (const float*)d_in[7];
    float* out = (float*)d_out;

    float* dinv    = (float*)d_ws;                  // 50176 f
    int*   indeg   = (int*)(dinv + 50176);          // 50176 i
    int*   rowptr  = indeg + 50176;                 // 50304 i
    int*   cursor  = rowptr + 50304;                // 50176 i
    int*   bsum    = cursor + 50176;                // 256 i
    int*   boff    = bsum + 256;                    // 256 i
    int*   csr     = boff + 256;                    // 800000 i (3.2 MB)
    unsigned short* Wth  = (unsigned short*)(csr + 800000);
    unsigned short* Wtl  = Wth + 65536;
    unsigned short* Wlth = Wtl + 65536;
    unsigned short* Wltl = Wlth + 65536;
    unsigned short* Woth = Wltl + 65536;            // 48x128
    unsigned short* Wotl = Woth + 6144;
    float* x0   = (float*)(Wotl + 6144);            // 6.4M f (residual anchor)
    float* res  = x0 + (size_t)N_NODES * HID;       // 6.4M f (c2*h + 0.1*x0)
    float* comb = res + (size_t)N_NODES * HID;      // 6.4M f (aggregate output)
    __half* g16 = (__half*)(comb + (size_t)N_NODES * HID);  // 6.4M halves (12.8 MB)

    const int edgeBlocks = (E_EDGES + 255) / 256;
    const int gemmBlocks = (N_NODES + 63) / 64;     // 782
    const int aggBlocks  = (N_NODES + 3) / 4;
    const int wprepBlocks = (2 * F_IN * HID + 48 * HID + 255) / 256;

    hipMemsetAsync(indeg, 0, N_NODES * sizeof(int), stream);
    indeg_count<<<edgeBlocks, 256, 0, stream>>>(ei, indeg);
    scan_p1<<<SCAN_BLOCKS, 256, 0, stream>>>(indeg, bsum, dinv);
    scan_p2<<<1, 256, 0, stream>>>(bsum, boff, rowptr);
    scan_p3<<<SCAN_BLOCKS, 256, 0, stream>>>(indeg, boff, rowptr, cursor);
    csr_fill<<<edgeBlocks, 256, 0, stream>>>(ei, cursor, csr);
    wprep<<<wprepBlocks, 256, 0, stream>>>(Wi, Wls, Wo, Wth, Wtl, Wlth, Wltl, Woth, Wotl);

    gemm_in_mfma<<<gemmBlocks, 256, 0, stream>>>(x, Wth, Wtl, bi, dinv, x0, res, g16);

    for (int l = 0; l < N_LAYERS - 1; l++) {
        aggregate<<<aggBlocks, 256, 0, stream>>>(rowptr, csr, dinv, g16, res, comb);
        gemm_layer_mfma<<<gemmBlocks, 256, 0, stream>>>(Wlth + (size_t)l * HID * HID,
                                                        Wltl + (size_t)l * HID * HID,
                                                        sbs + (size_t)l * HID, dinv,
                                                        comb, x0, res, g16);
    }
    // last layer: aggregate -> fused layer+output GEMM (h never hits global)
    aggregate<<<aggBlocks, 256, 0, stream>>>(rowptr, csr, dinv, g16, res, comb);
    gemm_layer_out<<<gemmBlocks, 256, 0, stream>>>(Wlth + (size_t)3 * HID * HID,
                                                   Wltl + (size_t)3 * HID * HID,
                                                   sbs + (size_t)3 * HID,
                                                   Woth, Wotl, bo, comb, out);
}

// Round 21
// 394.222 us; speedup vs baseline: 1.0617x; 1.0617x over previous
//
#include <hip/hip_runtime.h>
#include <hip/hip_fp16.h>

#define N_NODES 50000
#define E_EDGES 800000
#define F_IN 512
#define HID 128
#define N_LAYERS 4
#define C_OUT 40
#define SCAN_BLOCKS 196   // ceil(50000/256)

typedef __attribute__((ext_vector_type(8))) short bf16x8;
typedef __attribute__((ext_vector_type(4))) float f32x4;

#define MFMA16(a, b, c) __builtin_amdgcn_mfma_f32_16x16x32_bf16(a, b, c, 0, 0, 0)

// split fp32 into bf16 hi (RNE) + bf16 lo (residual); a ~= hi + lo with ~2^-17 rel error
__device__ __forceinline__ void split2(float a, unsigned short& hi, unsigned short& lo) {
    unsigned u = __float_as_uint(a);
    unsigned r = u + 0x7FFFu + ((u >> 16) & 1u);
    hi = (unsigned short)(r >> 16);
    float hf = __uint_as_float(((unsigned)hi) << 16);
    lo = (unsigned short)(__float_as_uint(a - hf) >> 16);
}

// async global->LDS 16B DMA
__device__ __forceinline__ void async16(void* lds, const void* g) {
    __builtin_amdgcn_global_load_lds(
        (const __attribute__((address_space(1))) unsigned*)g,
        (__attribute__((address_space(3))) unsigned*)lds, 16, 0, 0);
}

// ---------------- degree ----------------
__global__ void indeg_count(const int* __restrict__ ei, int* __restrict__ indeg) {
    int e = blockIdx.x * 256 + threadIdx.x;
    if (e < E_EDGES) {
        unsigned d = (unsigned)ei[E_EDGES + e];
        if (d < N_NODES) atomicAdd(&indeg[d], 1);
    }
}

// ---------------- 3-phase parallel exclusive scan (+ dinv fused in p1) ----------------
__global__ void scan_p1(const int* __restrict__ indeg, int* __restrict__ bsum,
                        float* __restrict__ dinv) {
    __shared__ int red[4];
    int i = blockIdx.x * 256 + threadIdx.x;
    int v = (i < N_NODES) ? indeg[i] : 0;
    if (i < N_NODES) dinv[i] = rsqrtf(1.0f + (float)v);   // +1 self-loop
    int s = v;
    #pragma unroll
    for (int off = 32; off > 0; off >>= 1) s += __shfl_down(s, off, 64);
    if ((threadIdx.x & 63) == 0) red[threadIdx.x >> 6] = s;
    __syncthreads();
    if (threadIdx.x == 0) bsum[blockIdx.x] = red[0] + red[1] + red[2] + red[3];
}

__launch_bounds__(256)
__global__ void scan_p2(const int* __restrict__ bsum, int* __restrict__ boff,
                        int* __restrict__ rowptr) {
    __shared__ int s[256];
    int t = threadIdx.x;
    int v = (t < SCAN_BLOCKS) ? bsum[t] : 0;
    s[t] = v;
    __syncthreads();
    #pragma unroll
    for (int off = 1; off < 256; off <<= 1) {
        int a = s[t];
        int b = (t >= off) ? s[t - off] : 0;
        __syncthreads();
        s[t] = a + b;
        __syncthreads();
    }
    if (t < SCAN_BLOCKS) boff[t] = (t == 0) ? 0 : s[t - 1];
    if (t == 255) rowptr[N_NODES] = s[SCAN_BLOCKS - 1];
}

__launch_bounds__(256)
__global__ void scan_p3(const int* __restrict__ indeg, const int* __restrict__ boff,
                        int* __restrict__ rowptr, int* __restrict__ cursor) {
    __shared__ int s[256];
    int t = threadIdx.x;
    int i = blockIdx.x * 256 + t;
    int v = (i < N_NODES) ? indeg[i] : 0;
    s[t] = v;
    __syncthreads();
    #pragma unroll
    for (int off = 1; off < 256; off <<= 1) {
        int a = s[t];
        int b = (t >= off) ? s[t - off] : 0;
        __syncthreads();
        s[t] = a + b;
        __syncthreads();
    }
    if (i < N_NODES) {
        int excl = boff[blockIdx.x] + s[t] - v;
        rowptr[i] = excl;
        cursor[i] = excl;
    }
}

// ---------------- CSR fill ----------------
__global__ void csr_fill(const int* __restrict__ ei, int* __restrict__ cursor,
                         int* __restrict__ csr) {
    int e = blockIdx.x * 256 + threadIdx.x;
    if (e < E_EDGES) {
        unsigned s = (unsigned)ei[e];
        unsigned d = (unsigned)ei[E_EDGES + e];
        if (s < N_NODES && d < N_NODES) {
            int pos = atomicAdd(&cursor[d], 1);
            csr[pos] = (int)s;
        }
    }
}

// ---------------- merged weight prep: fp32 W[K][N] -> hi/lo bf16 [N][K] (+ W_out padded) ----------------
__global__ void wprep(const float* __restrict__ Wi, const float* __restrict__ Wl,
                      const float* __restrict__ Wo,
                      unsigned short* __restrict__ Wth, unsigned short* __restrict__ Wtl,
                      unsigned short* __restrict__ Wlth, unsigned short* __restrict__ Wltl,
                      unsigned short* __restrict__ Woth, unsigned short* __restrict__ Wotl) {
    int idx = blockIdx.x * 256 + threadIdx.x;
    unsigned short hi, lo;
    if (idx < F_IN * HID) {
        int k = idx >> 7, n = idx & 127;
        split2(Wi[idx], hi, lo);
        Wth[(size_t)n * F_IN + k] = hi;
        Wtl[(size_t)n * F_IN + k] = lo;
    } else if (idx < 2 * F_IN * HID) {
        int j = idx - F_IN * HID;
        int l = j >> 14, rem = j & 16383;
        int k = rem >> 7, n = rem & 127;
        split2(Wl[j], hi, lo);
        Wlth[(size_t)l * HID * HID + n * HID + k] = hi;
        Wltl[(size_t)l * HID * HID + n * HID + k] = lo;
    } else if (idx < 2 * F_IN * HID + 48 * HID) {
        int j = idx - 2 * F_IN * HID;          // 0..6143
        int n = j >> 7, k = j & 127;           // n: padded col 0..47
        float w = (n < C_OUT) ? Wo[(size_t)k * C_OUT + n] : 0.f;
        split2(w, hi, lo);
        Woth[(size_t)n * HID + k] = hi;
        Wotl[(size_t)n * HID + k] = lo;
    }
}

// ---------------- input GEMM (MFMA split-bf16): x0 = relu(x@W_in+b), g16 = fp16(dinv*x0) ----------------
// EXACT r13 structure (68-71 µs proven best): BM=64, BK=32, 16 steps, single-buffered,
// LDS 24 KB -> 6 blocks/CU. No reg prefetch; bf16 A staging (fp32-DMA variant had conflicts).
__launch_bounds__(256)
__global__ void gemm_in_mfma(const float* __restrict__ x,
                             const unsigned short* __restrict__ Bth,
                             const unsigned short* __restrict__ Btl,
                             const float* __restrict__ bi,
                             const float* __restrict__ dinv,
                             float* __restrict__ x0out,
                             __half* __restrict__ g16) {
    __shared__ __align__(16) unsigned short Ah[64 * 32];    // 4 KB
    __shared__ __align__(16) unsigned short Al[64 * 32];    // 4 KB
    __shared__ __align__(16) unsigned short Bh[128 * 32];   // 8 KB
    __shared__ __align__(16) unsigned short Bl[128 * 32];   // 8 KB
    const int t = threadIdx.x;
    const int lane = t & 63;
    const int wv = t >> 6;
    const int wr = wv >> 1, wc = wv & 1;
    const int row0 = blockIdx.x * 64;
    const int fr = lane & 15;
    const int fkg = lane >> 4;          // 16B granule 0..3

    f32x4 acc[2][4] = {};

    for (int step = 0; step < 16; step++) {
        const int k0 = step * 32;
        #pragma unroll
        for (int i = 0; i < 2; i++) {
            int g = t + i * 256;                 // 0..511
            int n = g >> 2, kg = g & 3;
            int kgp = kg ^ ((n >> 1) & 3);
            size_t src = (size_t)n * F_IN + k0 + kgp * 8;
            async16(&Bh[g * 8], &Bth[src]);
            async16(&Bl[g * 8], &Btl[src]);
        }
        #pragma unroll
        for (int i = 0; i < 2; i++) {
            int q = t + i * 256;                 // 0..511
            int r = q >> 3, c4 = q & 7;
            int grow = row0 + r;
            float4 v = make_float4(0.f, 0.f, 0.f, 0.f);
            if (grow < N_NODES) v = *(const float4*)&x[(size_t)grow * F_IN + k0 + c4 * 4];
            ushort4 uh, ul;
            split2(v.x, uh.x, ul.x); split2(v.y, uh.y, ul.y);
            split2(v.z, uh.z, ul.z); split2(v.w, uh.w, ul.w);
            int gp = (c4 >> 1) ^ ((r >> 1) & 3);
            int idx = r * 32 + gp * 8 + (c4 & 1) * 4;
            *(ushort4*)&Ah[idx] = uh;
            *(ushort4*)&Al[idx] = ul;
        }
        __syncthreads();   // drains DMA + ds_writes

        bf16x8 ah[2], al[2];
        #pragma unroll
        for (int mt = 0; mt < 2; mt++) {
            int arow = wr * 32 + mt * 16 + fr;
            int aidx = arow * 32 + (fkg ^ ((arow >> 1) & 3)) * 8;
            ah[mt] = *(bf16x8*)&Ah[aidx];
            al[mt] = *(bf16x8*)&Al[aidx];
        }
        #pragma unroll
        for (int nt = 0; nt < 4; nt++) {
            int n = wc * 64 + nt * 16 + fr;
            int bidx = n * 32 + (fkg ^ ((n >> 1) & 3)) * 8;
            bf16x8 bh = *(bf16x8*)&Bh[bidx];
            bf16x8 bl = *(bf16x8*)&Bl[bidx];
            #pragma unroll
            for (int mt = 0; mt < 2; mt++) {
                acc[mt][nt] = MFMA16(al[mt], bh, acc[mt][nt]);
                acc[mt][nt] = MFMA16(ah[mt], bl, acc[mt][nt]);
                acc[mt][nt] = MFMA16(ah[mt], bh, acc[mt][nt]);
            }
        }
        __syncthreads();
    }

    const int dcol = lane & 15;
    const int dr0 = (lane >> 4) * 4;
    float dv[2][4];
    #pragma unroll
    for (int mt = 0; mt < 2; mt++)
        #pragma unroll
        for (int j = 0; j < 4; j++) {
            int grow = row0 + wr * 32 + mt * 16 + dr0 + j;
            dv[mt][j] = (grow < N_NODES) ? dinv[grow] : 0.f;
        }
    #pragma unroll
    for (int nt = 0; nt < 4; nt++) {
        int gcol = wc * 64 + nt * 16 + dcol;
        float b = bi[gcol];
        #pragma unroll
        for (int mt = 0; mt < 2; mt++) {
            #pragma unroll
            for (int j = 0; j < 4; j++) {
                int grow = row0 + wr * 32 + mt * 16 + dr0 + j;
                if (grow < N_NODES) {
                    float v = fmaxf(acc[mt][nt][j] + b, 0.f);
                    x0out[(size_t)grow * HID + gcol] = v;
                    g16[(size_t)grow * HID + gcol] = __float2half(dv[mt][j] * v);
                }
            }
        }
    }
}

// ---------------- aggregate: full wave per node, dword lanes, 16 loads in flight ----------------
// (r13/r17/r19-proven best: 46 µs/layer ~= 6.1 TB/s effective, 97% of achievable)
// comb = 0.8*dd*sum(g16[src]) + (0.8*dd^2+0.1)*h[d] + 0.1*x0[d]
__launch_bounds__(256)
__global__ void aggregate(const int* __restrict__ rowptr, const int* __restrict__ csr,
                          const float* __restrict__ dinv,
                          const __half* __restrict__ g16,
                          const float* __restrict__ h, const float* __restrict__ x0,
                          float* __restrict__ comb) {
    const int node = blockIdx.x * 4 + (threadIdx.x >> 6);
    const int lane = threadIdx.x & 63;
    if (node >= N_NODES) return;

    const unsigned* g32 = (const unsigned*)g16;   // lane owns dword = feats 2*lane, 2*lane+1
    const float dd = dinv[node];
    const int beg = rowptr[node];                 // wave-uniform -> scalar loads
    const int end = rowptr[node + 1];

    float a0 = 0.f, a1 = 0.f, b0 = 0.f, b1 = 0.f;

    #define GACC(r, i) { \
        __half2 p = *(__half2*)&(r); \
        float2 f = __half22float2(p); \
        if ((i) & 1) { b0 += f.x; b1 += f.y; } else { a0 += f.x; a1 += f.y; } }

    int e = beg;
    for (; e + 16 <= end; e += 16) {
        unsigned r[16];
        #pragma unroll
        for (int i = 0; i < 16; i++) r[i] = g32[(size_t)csr[e + i] * 64 + lane];
        #pragma unroll
        for (int i = 0; i < 16; i++) GACC(r[i], i)
    }
    for (; e + 4 <= end; e += 4) {
        unsigned r[4];
        #pragma unroll
        for (int i = 0; i < 4; i++) r[i] = g32[(size_t)csr[e + i] * 64 + lane];
        #pragma unroll
        for (int i = 0; i < 4; i++) GACC(r[i], i)
    }
    for (; e < end; e++) {
        unsigned r = g32[(size_t)csr[e] * 64 + lane];
        GACC(r, 0)
    }
    #undef GACC

    float s0 = a0 + b0, s1 = a1 + b1;
    const float c1 = 0.8f * dd;
    const float c2 = 0.8f * dd * dd + 0.1f;
    float2 hv = ((const float2*)h)[(size_t)node * 64 + lane];
    float2 xv = ((const float2*)x0)[(size_t)node * 64 + lane];
    float2 o;
    o.x = fmaf(c1, s0, fmaf(c2, hv.x, 0.1f * xv.x));
    o.y = fmaf(c1, s1, fmaf(c2, hv.y, 0.1f * xv.y));
    ((float2*)comb)[(size_t)node * 64 + lane] = o;
}

// ---------------- layer GEMM (MFMA split-bf16, in place): h <- SReLU(comb @ W), g16 ----------------
// BK=32 single-buffered B chunk -> LDS 48 KB -> 3 blocks/CU. (r14-verified)
__launch_bounds__(256)
__global__ void gemm_layer_mfma(const unsigned short* __restrict__ Bth,
                                const unsigned short* __restrict__ Btl,
                                const float* __restrict__ sb,
                                const float* __restrict__ dinv,
                                float* __restrict__ comb,
                                __half* __restrict__ g16) {
    __shared__ __align__(16) unsigned short Ah[64 * 128];   // 16 KB
    __shared__ __align__(16) unsigned short Al[64 * 128];   // 16 KB
    __shared__ __align__(16) unsigned short Bh[128 * 32];   // 8 KB
    __shared__ __align__(16) unsigned short Bl[128 * 32];   // 8 KB
    const int t = threadIdx.x;
    const int lane = t & 63;
    const int wv = t >> 6;
    const int wr = wv >> 1, wc = wv & 1;
    const int row0 = blockIdx.x * 64;
    const int fr = lane & 15;
    const int fkg = lane >> 4;

    f32x4 acc[2][4] = {};

    auto stageB = [&](int k0) {
        #pragma unroll
        for (int i = 0; i < 2; i++) {
            int g = t + i * 256;
            int n = g >> 2, kg = g & 3;
            int kgp = kg ^ ((n >> 1) & 3);
            size_t src = (size_t)n * HID + k0 + kgp * 8;
            async16(&Bh[g * 8], &Bth[src]);
            async16(&Bl[g * 8], &Btl[src]);
        }
    };

    stageB(0);
    #pragma unroll
    for (int i = 0; i < 8; i++) {
        int q = t + i * 256;
        int r = q >> 5, c4 = q & 31;
        int grow = row0 + r;
        float4 v = make_float4(0.f, 0.f, 0.f, 0.f);
        if (grow < N_NODES) v = *(const float4*)&comb[(size_t)grow * HID + c4 * 4];
        ushort4 uh, ul;
        split2(v.x, uh.x, ul.x); split2(v.y, uh.y, ul.y);
        split2(v.z, uh.z, ul.z); split2(v.w, uh.w, ul.w);
        int idx = (r * 128 + c4 * 4) ^ ((r & 7) << 3);
        *(ushort4*)&Ah[idx] = uh;
        *(ushort4*)&Al[idx] = ul;
    }
    __syncthreads();

    #pragma unroll
    for (int step = 0; step < 4; step++) {
        bf16x8 ah[2], al[2];
        #pragma unroll
        for (int mt = 0; mt < 2; mt++) {
            int arow = wr * 32 + mt * 16 + fr;
            int aidx = (arow * 128 + step * 32 + fkg * 8) ^ ((arow & 7) << 3);
            ah[mt] = *(bf16x8*)&Ah[aidx];
            al[mt] = *(bf16x8*)&Al[aidx];
        }
        #pragma unroll
        for (int nt = 0; nt < 4; nt++) {
            int n = wc * 64 + nt * 16 + fr;
            int bidx = n * 32 + (fkg ^ ((n >> 1) & 3)) * 8;
            bf16x8 bh = *(bf16x8*)&Bh[bidx];
            bf16x8 bl = *(bf16x8*)&Bl[bidx];
            #pragma unroll
            for (int mt = 0; mt < 2; mt++) {
                acc[mt][nt] = MFMA16(al[mt], bh, acc[mt][nt]);
                acc[mt][nt] = MFMA16(ah[mt], bl, acc[mt][nt]);
                acc[mt][nt] = MFMA16(ah[mt], bh, acc[mt][nt]);
            }
        }
        __syncthreads();
        if (step < 3) {
            stageB((step + 1) * 32);
            __syncthreads();
        }
    }

    const int dcol = lane & 15;
    const int dr0 = (lane >> 4) * 4;
    float dv[2][4];
    #pragma unroll
    for (int mt = 0; mt < 2; mt++)
        #pragma unroll
        for (int j = 0; j < 4; j++) {
            int grow = row0 + wr * 32 + mt * 16 + dr0 + j;
            dv[mt][j] = (grow < N_NODES) ? dinv[grow] : 0.f;
        }
    #pragma unroll
    for (int nt = 0; nt < 4; nt++) {
        int gcol = wc * 64 + nt * 16 + dcol;
        float s = sb[gcol];
        #pragma unroll
        for (int mt = 0; mt < 2; mt++) {
            #pragma unroll
            for (int j = 0; j < 4; j++) {
                int grow = row0 + wr * 32 + mt * 16 + dr0 + j;
                if (grow < N_NODES) {
                    float v = fmaxf(acc[mt][nt][j], s);
                    comb[(size_t)grow * HID + gcol] = v;
                    g16[(size_t)grow * HID + gcol] = __float2half(dv[mt][j] * v);
                }
            }
        }
    }
}

// ---------------- last layer GEMM + fused output GEMM (r15-verified win) ----------------
__launch_bounds__(256)
__global__ void gemm_layer_out(const unsigned short* __restrict__ Bth,
                               const unsigned short* __restrict__ Btl,
                               const float* __restrict__ sb,
                               const unsigned short* __restrict__ Woth,
                               const unsigned short* __restrict__ Wotl,
                               const float* __restrict__ bo,
                               const float* __restrict__ comb,
                               float* __restrict__ out) {
    __shared__ __align__(16) unsigned short Ah[64 * 128];
    __shared__ __align__(16) unsigned short Al[64 * 128];
    __shared__ __align__(16) unsigned short Bh[128 * 32];
    __shared__ __align__(16) unsigned short Bl[128 * 32];
    const int t = threadIdx.x;
    const int lane = t & 63;
    const int wv = t >> 6;
    const int wr = wv >> 1, wc = wv & 1;
    const int row0 = blockIdx.x * 64;
    const int fr = lane & 15;
    const int fkg = lane >> 4;

    f32x4 acc[2][4] = {};

    auto stageB = [&](int k0) {
        #pragma unroll
        for (int i = 0; i < 2; i++) {
            int g = t + i * 256;
            int n = g >> 2, kg = g & 3;
            int kgp = kg ^ ((n >> 1) & 3);
            size_t src = (size_t)n * HID + k0 + kgp * 8;
            async16(&Bh[g * 8], &Bth[src]);
            async16(&Bl[g * 8], &Btl[src]);
        }
    };

    stageB(0);
    #pragma unroll
    for (int i = 0; i < 8; i++) {
        int q = t + i * 256;
        int r = q >> 5, c4 = q & 31;
        int grow = row0 + r;
        float4 v = make_float4(0.f, 0.f, 0.f, 0.f);
        if (grow < N_NODES) v = *(const float4*)&comb[(size_t)grow * HID + c4 * 4];
        ushort4 uh, ul;
        split2(v.x, uh.x, ul.x); split2(v.y, uh.y, ul.y);
        split2(v.z, uh.z, ul.z); split2(v.w, uh.w, ul.w);
        int idx = (r * 128 + c4 * 4) ^ ((r & 7) << 3);
        *(ushort4*)&Ah[idx] = uh;
        *(ushort4*)&Al[idx] = ul;
    }
    __syncthreads();

    #pragma unroll
    for (int step = 0; step < 4; step++) {
        bf16x8 ah[2], al[2];
        #pragma unroll
        for (int mt = 0; mt < 2; mt++) {
            int arow = wr * 32 + mt * 16 + fr;
            int aidx = (arow * 128 + step * 32 + fkg * 8) ^ ((arow & 7) << 3);
            ah[mt] = *(bf16x8*)&Ah[aidx];
            al[mt] = *(bf16x8*)&Al[aidx];
        }
        #pragma unroll
        for (int nt = 0; nt < 4; nt++) {
            int n = wc * 64 + nt * 16 + fr;
            int bidx = n * 32 + (fkg ^ ((n >> 1) & 3)) * 8;
            bf16x8 bh = *(bf16x8*)&Bh[bidx];
            bf16x8 bl = *(bf16x8*)&Bl[bidx];
            #pragma unroll
            for (int mt = 0; mt < 2; mt++) {
                acc[mt][nt] = MFMA16(al[mt], bh, acc[mt][nt]);
                acc[mt][nt] = MFMA16(ah[mt], bl, acc[mt][nt]);
                acc[mt][nt] = MFMA16(ah[mt], bh, acc[mt][nt]);
            }
        }
        __syncthreads();
        if (step < 3) {
            stageB((step + 1) * 32);
            __syncthreads();
        }
    }

    // SReLU -> h4 back into A-LDS (split bf16, same swizzle; A is free now)
    const int dcol = lane & 15;
    const int dr0 = (lane >> 4) * 4;
    #pragma unroll
    for (int nt = 0; nt < 4; nt++) {
        int col = wc * 64 + nt * 16 + dcol;
        float s = sb[col];
        #pragma unroll
        for (int mt = 0; mt < 2; mt++) {
            #pragma unroll
            for (int j = 0; j < 4; j++) {
                int row = wr * 32 + mt * 16 + dr0 + j;
                float v = fmaxf(acc[mt][nt][j], s);
                unsigned short hi, lo;
                split2(v, hi, lo);
                int idx = (row * 128 + col) ^ ((row & 7) << 3);
                Ah[idx] = hi;
                Al[idx] = lo;
            }
        }
    }
    __syncthreads();

    // out phase: wave wv owns rows wv*16..+15; 3 n-tiles (48 padded cols), K=128
    f32x4 oacc[3] = {};
    #pragma unroll
    for (int kk = 0; kk < 4; kk++) {
        int arow = wv * 16 + fr;
        int aidx = (arow * 128 + kk * 32 + fkg * 8) ^ ((arow & 7) << 3);
        bf16x8 ah = *(bf16x8*)&Ah[aidx];
        bf16x8 al = *(bf16x8*)&Al[aidx];
        #pragma unroll
        for (int nt = 0; nt < 3; nt++) {
            size_t boff = (size_t)(nt * 16 + fr) * HID + kk * 32 + fkg * 8;
            bf16x8 bh = *(const bf16x8*)&Woth[boff];
            bf16x8 bl = *(const bf16x8*)&Wotl[boff];
            oacc[nt] = MFMA16(al, bh, oacc[nt]);
            oacc[nt] = MFMA16(ah, bl, oacc[nt]);
            oacc[nt] = MFMA16(ah, bh, oacc[nt]);
        }
    }
    #pragma unroll
    for (int nt = 0; nt < 3; nt++) {
        int gcol = nt * 16 + dcol;
        if (gcol < C_OUT) {
            float b = bo[gcol];
            #pragma unroll
            for (int j = 0; j < 4; j++) {
                int grow = row0 + wv * 16 + dr0 + j;
                if (grow < N_NODES)
                    out[(size_t)grow * C_OUT + gcol] = oacc[nt][j] + b;
            }
        }
    }
}

// ---------------- launch ----------------
extern "C" void kernel_launch(void* const* d_in, const int* in_sizes, int n_in,
                              void* d_out, int out_size, void* d_ws, size_t ws_size,
                              hipStream_t stream) {
    const float* x   = (const float*)d_in[0];
    const int*   ei  = (const int*)d_in[1];
    const float* Wi  = (const float*)d_in[2];
    const float* bi  = (const float*)d_in[3];
    const float* Wls = (const float*)d_in[4];
    const float* sbs = (const float*)d_in[5];
    const float* Wo  = (const float*)d_in[6];
    const float* bo  = (const float*)d_in[7];
    float* out = (float*)d_out;

    float* dinv    = (float*)d_ws;                  // 50176 f
    int*   indeg   = (int*)(dinv + 50176);          // 50176 i
    int*   rowptr  = indeg + 50176;                 // 50304 i
    int*   cursor  = rowptr + 50304;                // 50176 i
    int*   bsum    = cursor + 50176;                // 256 i
    int*   boff    = bsum + 256;                    // 256 i
    int*   csr     = boff + 256;                    // 800000 i (3.2 MB)
    unsigned short* Wth  = (unsigned short*)(csr + 800000);
    unsigned short* Wtl  = Wth + 65536;
    unsigned short* Wlth = Wtl + 65536;
    unsigned short* Wltl = Wlth + 65536;
    unsigned short* Woth = Wltl + 65536;            // 48x128
    unsigned short* Wotl = Woth + 6144;
    float* x0  = (float*)(Wotl + 6144);             // 6.4M f (residual anchor)
    float* hB  = x0 + (size_t)N_NODES * HID;        // 6.4M f
    float* hC  = hB + (size_t)N_NODES * HID;        // 6.4M f
    __half* g16 = (__half*)(hC + (size_t)N_NODES * HID);  // 6.4M halves (12.8 MB), row-major

    const int edgeBlocks = (E_EDGES + 255) / 256;
    const int gemmBlocks = (N_NODES + 63) / 64;     // 782
    const int aggBlocks  = (N_NODES + 3) / 4;
    const int wprepBlocks = (2 * F_IN * HID + 48 * HID + 255) / 256;

    hipMemsetAsync(indeg, 0, N_NODES * sizeof(int), stream);
    indeg_count<<<edgeBlocks, 256, 0, stream>>>(ei, indeg);
    scan_p1<<<SCAN_BLOCKS, 256, 0, stream>>>(indeg, bsum, dinv);
    scan_p2<<<1, 256, 0, stream>>>(bsum, boff, rowptr);
    scan_p3<<<SCAN_BLOCKS, 256, 0, stream>>>(indeg, boff, rowptr, cursor);
    csr_fill<<<edgeBlocks, 256, 0, stream>>>(ei, cursor, csr);
    wprep<<<wprepBlocks, 256, 0, stream>>>(Wi, Wls, Wo, Wth, Wtl, Wlth, Wltl, Woth, Wotl);

    gemm_in_mfma<<<gemmBlocks, 256, 0, stream>>>(x, Wth, Wtl, bi, dinv, x0, g16);

    float* h = x0;
    for (int l = 0; l < N_LAYERS - 1; l++) {
        float* next = (l & 1) ? hC : hB;
        aggregate<<<aggBlocks, 256, 0, stream>>>(rowptr, csr, dinv, g16, h, x0, next);
        gemm_layer_mfma<<<gemmBlocks, 256, 0, stream>>>(Wlth + (size_t)l * HID * HID,
                                                        Wltl + (size_t)l * HID * HID,
                                                        sbs + (size_t)l * HID, dinv,
                                                        next, g16);
        h = next;
    }
    // last layer: aggregate -> fused layer+output GEMM (h4 never hits global)
    aggregate<<<aggBlocks, 256, 0, stream>>>(rowptr, csr, dinv, g16, h, x0, hC);
    gemm_layer_out<<<gemmBlocks, 256, 0, stream>>>(Wlth + (size_t)3 * HID * HID,
                                                   Wltl + (size_t)3 * HID * HID,
                                                   sbs + (size_t)3 * HID,
                                                   Woth, Wotl, bo, hC, out);
}